// Round 4
// baseline (119.148 us; speedup 1.0000x reference)
//
#include <hip/hip_runtime.h>

#define SS 17
#define AA 5
#define CC 20
#define BATCH 256
#define GG 32
#define HWC (SS * SS)        // 289
#define NP (HWC * AA)        // 1445
#define SPLIT 4
#define NTHREADS 256
#define NPART (BATCH * SPLIT)
#define POISON 0xAAAAAAAAu   // harness re-poisons d_ws to 0xAA bytes pre-launch

__global__ __launch_bounds__(NTHREADS) void yolo_loss_fused(
    const float* __restrict__ bbox,    // (B, HW, A, 4)
    const float* __restrict__ ioup,    // (B, HW, A, 1)
    const float* __restrict__ score,   // (B, HW, A, C)
    const float* __restrict__ tgt,     // (B*G, 6)
    const float* __restrict__ anchors, // (A, 2)
    float*    __restrict__ part,       // (NPART,) partial sums (d_ws)
    unsigned* __restrict__ cnt,        // 1 counter (d_ws), starts at POISON
    float*    __restrict__ out)
{
    const int b    = blockIdx.x;
    const int spl  = blockIdx.y;
    const int tid  = threadIdx.x;
    const int flat = b * SPLIT + spl;

    __shared__ float gx1[GG], gy1[GG], gx2[GG], gy2[GG], garea[GG];
    __shared__ float tarb[GG][4];
    __shared__ int   gcls[GG];
    __shared__ float anc[AA][2];
    __shared__ short assign[NP + 1];
    __shared__ float wsum[NTHREADS / 64];
    __shared__ unsigned last_flag;

    // Phase A: init assignment table + load normalized anchors
    for (int p = tid; p < NP; p += NTHREADS) assign[p] = -1;
    if (tid < AA * 2) ((float*)anc)[tid] = anchors[tid] * (1.0f / 17.0f);
    __syncthreads();

    // Phase B: per-GT preprocessing (32 threads). Cells are distinct per
    // image by construction, so no (cell,anchor) write collisions.
    if (tid < GG) {
        const float* t = tgt + (size_t)(b * GG + tid) * 6;
        int   cls = (int)t[1];
        float x1 = t[2], y1 = t[3], x2 = t[4], y2 = t[5];
        float cx = (x1 + x2) * 0.5f, cy = (y1 + y2) * 0.5f;
        float gw = x2 - x1, gh = y2 - y1;
        float cxs = cx * (float)SS, cys = cy * (float)SS;
        int ci = (int)floorf(cxs), cj = (int)floorf(cys);
        gx1[tid] = x1; gy1[tid] = y1; gx2[tid] = x2; gy2[tid] = y2;
        garea[tid] = gw * gh;
        tarb[tid][0] = cxs - (float)ci;
        tarb[tid][1] = cys - (float)cj;
        tarb[tid][2] = gw;
        tarb[tid][3] = gh;
        gcls[tid] = cls;
        // anchor argmax (first max wins, matching jnp.argmax)
        float best = -1.0f; int bi = 0;
        for (int a = 0; a < AA; a++) {
            float aw = anc[a][0], ah = anc[a][1];
            float inter = fminf(aw, gw) * fminf(ah, gh);
            float u = aw * ah + gw * gh - inter;
            float v = inter / u;
            if (v > best) { best = v; bi = a; }
        }
        int cell = ci * SS + cj;
        assign[cell * AA + bi] = (short)tid;
    }
    __syncthreads();

    // Phase C: main loop over pred boxes
    float acc = 0.0f;
    const int base = b * NP;
    for (int p = spl * NTHREADS + tid; p < NP; p += NTHREADS * SPLIT) {
        float4 bb = ((const float4*)bbox)[base + p];
        float  ip = ioup[base + p];
        int hw = p / AA;
        int a  = p - hw * AA;
        int i  = hw / SS;
        int j  = hw - i * SS;

        float px = (bb.x + (float)i) * (1.0f / SS);
        float py = (bb.y + (float)j) * (1.0f / SS);
        float pw = bb.z * anc[a][0] * (1.0f / SS);
        float ph = bb.w * anc[a][1] * (1.0f / SS);
        float px1 = px - pw * 0.5f, py1 = py - ph * 0.5f;
        float px2 = px + pw * 0.5f, py2 = py + ph * 0.5f;
        float parea = (px2 - px1) * (py2 - py1);

        int ga = (int)assign[p];
        float best = 0.0f;   // IoU >= 0 always
        float iou_t = 0.0f;
        #pragma unroll 8
        for (int g = 0; g < GG; g++) {
            float lx = fmaxf(px1, gx1[g]);
            float ly = fmaxf(py1, gy1[g]);
            float rx = fminf(px2, gx2[g]);
            float ry = fminf(py2, gy2[g]);
            float w  = fmaxf(rx - lx, 0.0f);
            float h  = fmaxf(ry - ly, 0.0f);
            float inter = w * h;
            float iou = inter / (parea + garea[g] - inter);
            best = fmaxf(best, iou);
            if (g == ga) iou_t = iou;
        }

        if (ga >= 0) {
            // box loss (mask = 1)
            float dx = bb.x - tarb[ga][0];
            float dy = bb.y - tarb[ga][1];
            float dw = bb.z - tarb[ga][2];
            float dh = bb.w - tarb[ga][3];
            acc += dx * dx + dy * dy + dw * dw + dh * dh;
            // iou loss: mask = OBJ_SCALE*(1-ip), target = iou_t
            float m = 5.0f * (1.0f - ip);
            float d = ip - iou_t;
            acc += (m * m) * (d * d);
            // class loss: mask = 1 on this row only; row is 80B = 16B-aligned
            const float4* sp4 = (const float4*)(score + (size_t)(base + p) * CC);
            int cls = gcls[ga];
            float csum = 0.0f;
            #pragma unroll
            for (int c4 = 0; c4 < CC / 4; c4++) {
                float4 sv = sp4[c4];
                float v0 = sv.x - (4 * c4 + 0 == cls ? 1.0f : 0.0f);
                float v1 = sv.y - (4 * c4 + 1 == cls ? 1.0f : 0.0f);
                float v2 = sv.z - (4 * c4 + 2 == cls ? 1.0f : 0.0f);
                float v3 = sv.w - (4 * c4 + 3 == cls ? 1.0f : 0.0f);
                csum += v0 * v0 + v1 * v1 + v2 * v2 + v3 * v3;
            }
            acc += csum;
        } else {
            // box loss (mask = 0.01 -> 1e-4 factor), target = (0.5,0.5,1,1)
            float dx = bb.x - 0.5f, dy = bb.y - 0.5f;
            float dw = bb.z - 1.0f, dh = bb.w - 1.0f;
            acc += 1e-4f * (dx * dx + dy * dy + dw * dw + dh * dh);
            // noobj iou loss: mask = -ip, target 0 -> ip^4 (only if best<=0.6)
            if (best <= 0.6f) {
                float q = ip * ip;
                acc += q * q;
            }
        }
    }

    // Phase D: block reduction (wave64 shuffle, then LDS across 4 waves)
    #pragma unroll
    for (int off = 32; off > 0; off >>= 1)
        acc += __shfl_down(acc, off, 64);
    if ((tid & 63) == 0) wsum[tid >> 6] = acc;
    __syncthreads();

    // Publish partial, then last-ARRIVER (no spinning anywhere) reduces.
    // Counter starts at POISON every launch (harness re-poisons d_ws).
    if (tid == 0) {
        part[flat] = wsum[0] + wsum[1] + wsum[2] + wsum[3];
        __threadfence();  // device-scope: partial visible before counter bump
        unsigned old = __hip_atomic_fetch_add(cnt, 1u, __ATOMIC_ACQ_REL,
                                              __HIP_MEMORY_SCOPE_AGENT);
        last_flag = (old == POISON + (unsigned)(NPART - 1)) ? 1u : 0u;
    }
    __syncthreads();

    if (last_flag) {
        float s = 0.0f;
        #pragma unroll
        for (int k = 0; k < NPART / NTHREADS; k++)
            s += __hip_atomic_load(&part[k * NTHREADS + tid],
                                   __ATOMIC_RELAXED, __HIP_MEMORY_SCOPE_AGENT);
        #pragma unroll
        for (int off = 32; off > 0; off >>= 1)
            s += __shfl_down(s, off, 64);
        __syncthreads();           // wsum reuse hazard
        if ((tid & 63) == 0) wsum[tid >> 6] = s;
        __syncthreads();
        if (tid == 0)
            out[0] = (wsum[0] + wsum[1] + wsum[2] + wsum[3]) * (1.0f / (float)GG);
    }
}

extern "C" void kernel_launch(void* const* d_in, const int* in_sizes, int n_in,
                              void* d_out, int out_size, void* d_ws, size_t ws_size,
                              hipStream_t stream) {
    const float* bbox    = (const float*)d_in[0];
    const float* ioup    = (const float*)d_in[1];
    const float* score   = (const float*)d_in[2];
    const float* tgt     = (const float*)d_in[3];
    const float* anchors = (const float*)d_in[4];
    float*    out  = (float*)d_out;
    float*    part = (float*)d_ws;                      // NPART floats
    unsigned* cnt  = (unsigned*)((char*)d_ws + 8192);   // 1 u32, starts POISON

    dim3 grid(BATCH, SPLIT);
    yolo_loss_fused<<<grid, NTHREADS, 0, stream>>>(bbox, ioup, score, tgt,
                                                   anchors, part, cnt, out);
}

// Round 5
// 88.648 us; speedup vs baseline: 1.3441x; 1.3441x over previous
//
#include <hip/hip_runtime.h>

#define SS 17
#define AA 5
#define CC 20
#define BATCH 256
#define GG 32
#define HWC (SS * SS)        // 289
#define NP (HWC * AA)        // 1445
#define SPLIT 4
#define CHUNK 362            // ceil(NP / SPLIT);每 block contiguous chunk
#define NTHREADS 256
#define NPART (BATCH * SPLIT)

__global__ __launch_bounds__(NTHREADS) void yolo_loss_kernel(
    const float* __restrict__ bbox,    // (B, HW, A, 4)
    const float* __restrict__ ioup,    // (B, HW, A, 1)
    const float* __restrict__ score,   // (B, HW, A, C)
    const float* __restrict__ tgt,     // (B*G, 6)
    const float* __restrict__ anchors, // (A, 2)
    float* __restrict__ part)          // (NPART,) partial sums
{
    const int b   = blockIdx.x;
    const int spl = blockIdx.y;
    const int tid = threadIdx.x;

    __shared__ float4 gbox[GG];        // x1,y1,x2,y2
    __shared__ float4 tarb[GG];        // tx,ty,tw,th
    __shared__ int    gcls[GG];
    __shared__ float  anc[AA][2];
    __shared__ short  assign[NP + 3];
    __shared__ float  wsum[NTHREADS / 64];

    // Phase A: init assignment table + load normalized anchors
    for (int p = tid; p < NP; p += NTHREADS) assign[p] = -1;
    if (tid < AA * 2) ((float*)anc)[tid] = anchors[tid] * (1.0f / 17.0f);
    __syncthreads();

    // Phase B: per-GT preprocessing (32 threads). Cells distinct per image.
    if (tid < GG) {
        const float* t = tgt + (size_t)(b * GG + tid) * 6;
        int   cls = (int)t[1];
        float x1 = t[2], y1 = t[3], x2 = t[4], y2 = t[5];
        float cx = (x1 + x2) * 0.5f, cy = (y1 + y2) * 0.5f;
        float gw = x2 - x1, gh = y2 - y1;
        float cxs = cx * (float)SS, cys = cy * (float)SS;
        int ci = (int)floorf(cxs), cj = (int)floorf(cys);
        gbox[tid] = make_float4(x1, y1, x2, y2);
        tarb[tid] = make_float4(cxs - (float)ci, cys - (float)cj, gw, gh);
        gcls[tid] = cls;
        // anchor argmax (first max wins, matching jnp.argmax)
        float best = -1.0f; int bi = 0;
        for (int a = 0; a < AA; a++) {
            float aw = anc[a][0], ah = anc[a][1];
            float inter = fminf(aw, gw) * fminf(ah, gh);
            float v = inter / (aw * ah + gw * gh - inter);
            if (v > best) { best = v; bi = a; }
        }
        assign[(ci * SS + cj) * AA + bi] = (short)tid;
    }
    __syncthreads();

    // Phase C: this block covers p in [base, end); p0 always valid,
    // p1 = p0+256 valid only for low tids. Both share ONE g-loop.
    const int pbase = spl * CHUNK;
    const int pend  = min(NP, pbase + CHUNK);
    const int gbase = b * NP;

    const int p0 = pbase + tid;                 // always < pend (CHUNK>256+?)
    const int p1 = p0 + NTHREADS;
    const bool v1 = (p1 < pend);
    const int p1c = v1 ? p1 : p0;               // clamp for safe loads

    // Global loads (coalesced float4 / float)
    float4 bb0 = ((const float4*)bbox)[gbase + p0];
    float4 bb1 = ((const float4*)bbox)[gbase + p1c];
    float  ip0 = ioup[gbase + p0];
    float  ip1 = ioup[gbase + p1c];

    // Decode pred boxes (corner form) for both p's
    float px10, py10, px20, py20, pa0;
    float px11, py11, px21, py21, pa1;
    {
        int hw = p0 / AA, a = p0 - hw * AA;
        int i = hw / SS,  j = hw - i * SS;
        float px = (bb0.x + (float)i) * (1.0f / SS);
        float py = (bb0.y + (float)j) * (1.0f / SS);
        float pw = bb0.z * anc[a][0] * (1.0f / SS);
        float ph = bb0.w * anc[a][1] * (1.0f / SS);
        px10 = px - pw * 0.5f; py10 = py - ph * 0.5f;
        px20 = px + pw * 0.5f; py20 = py + ph * 0.5f;
        pa0  = (px20 - px10) * (py20 - py10);
    }
    {
        int hw = p1c / AA, a = p1c - hw * AA;
        int i = hw / SS,   j = hw - i * SS;
        float px = (bb1.x + (float)i) * (1.0f / SS);
        float py = (bb1.y + (float)j) * (1.0f / SS);
        float pw = bb1.z * anc[a][0] * (1.0f / SS);
        float ph = bb1.w * anc[a][1] * (1.0f / SS);
        px11 = px - pw * 0.5f; py11 = py - ph * 0.5f;
        px21 = px + pw * 0.5f; py21 = py + ph * 0.5f;
        pa1  = (px21 - px11) * (py21 - py11);
    }

    // Fused g-loop: track max of (inter - 0.375*(parea+garea)).
    // best_iou <= 0.6  <=>  anyhit <= 0   (division-free transform)
    float any0 = -1.0f, any1 = -1.0f;
    #pragma unroll 8
    for (int g = 0; g < GG; g++) {
        float4 gb = gbox[g];                    // ds_read_b128, broadcast
        float garea = (gb.z - gb.x) * (gb.w - gb.y);
        {
            float w = fminf(px20, gb.z) - fmaxf(px10, gb.x);
            float h = fminf(py20, gb.w) - fmaxf(py10, gb.y);
            float inter = fmaxf(w, 0.0f) * fmaxf(h, 0.0f);
            any0 = fmaxf(any0, __builtin_fmaf(-0.375f, pa0 + garea, inter));
        }
        {
            float w = fminf(px21, gb.z) - fmaxf(px11, gb.x);
            float h = fminf(py21, gb.w) - fmaxf(py11, gb.y);
            float inter = fmaxf(w, 0.0f) * fmaxf(h, 0.0f);
            any1 = fmaxf(any1, __builtin_fmaf(-0.375f, pa1 + garea, inter));
        }
    }

    float acc = 0.0f;

    // Epilogue p0 (always valid)
    {
        int ga = (int)assign[p0];
        if (ga >= 0) {
            float4 gb = gbox[ga];
            float w = fmaxf(fminf(px20, gb.z) - fmaxf(px10, gb.x), 0.0f);
            float h = fmaxf(fminf(py20, gb.w) - fmaxf(py10, gb.y), 0.0f);
            float inter = w * h;
            float garea = (gb.z - gb.x) * (gb.w - gb.y);
            float iou_t = inter / (pa0 + garea - inter);
            float4 tb = tarb[ga];
            float dx = bb0.x - tb.x, dy = bb0.y - tb.y;
            float dw = bb0.z - tb.z, dh = bb0.w - tb.w;
            acc += dx * dx + dy * dy + dw * dw + dh * dh;
            float m = 5.0f * (1.0f - ip0);
            float d = ip0 - iou_t;
            acc += (m * m) * (d * d);
            const float4* sp4 = (const float4*)(score + (size_t)(gbase + p0) * CC);
            int cls = gcls[ga];
            #pragma unroll
            for (int c4 = 0; c4 < CC / 4; c4++) {
                float4 sv = sp4[c4];
                float v0 = sv.x - (4 * c4 + 0 == cls ? 1.0f : 0.0f);
                float v1v = sv.y - (4 * c4 + 1 == cls ? 1.0f : 0.0f);
                float v2 = sv.z - (4 * c4 + 2 == cls ? 1.0f : 0.0f);
                float v3 = sv.w - (4 * c4 + 3 == cls ? 1.0f : 0.0f);
                acc += v0 * v0 + v1v * v1v + v2 * v2 + v3 * v3;
            }
        } else {
            float dx = bb0.x - 0.5f, dy = bb0.y - 0.5f;
            float dw = bb0.z - 1.0f, dh = bb0.w - 1.0f;
            acc += 1e-4f * (dx * dx + dy * dy + dw * dw + dh * dh);
            if (any0 <= 0.0f) { float q = ip0 * ip0; acc += q * q; }
        }
    }

    // Epilogue p1 (predicated)
    if (v1) {
        int ga = (int)assign[p1];
        if (ga >= 0) {
            float4 gb = gbox[ga];
            float w = fmaxf(fminf(px21, gb.z) - fmaxf(px11, gb.x), 0.0f);
            float h = fmaxf(fminf(py21, gb.w) - fmaxf(py11, gb.y), 0.0f);
            float inter = w * h;
            float garea = (gb.z - gb.x) * (gb.w - gb.y);
            float iou_t = inter / (pa1 + garea - inter);
            float4 tb = tarb[ga];
            float dx = bb1.x - tb.x, dy = bb1.y - tb.y;
            float dw = bb1.z - tb.z, dh = bb1.w - tb.w;
            acc += dx * dx + dy * dy + dw * dw + dh * dh;
            float m = 5.0f * (1.0f - ip1);
            float d = ip1 - iou_t;
            acc += (m * m) * (d * d);
            const float4* sp4 = (const float4*)(score + (size_t)(gbase + p1) * CC);
            int cls = gcls[ga];
            #pragma unroll
            for (int c4 = 0; c4 < CC / 4; c4++) {
                float4 sv = sp4[c4];
                float v0 = sv.x - (4 * c4 + 0 == cls ? 1.0f : 0.0f);
                float v1v = sv.y - (4 * c4 + 1 == cls ? 1.0f : 0.0f);
                float v2 = sv.z - (4 * c4 + 2 == cls ? 1.0f : 0.0f);
                float v3 = sv.w - (4 * c4 + 3 == cls ? 1.0f : 0.0f);
                acc += v0 * v0 + v1v * v1v + v2 * v2 + v3 * v3;
            }
        } else {
            float dx = bb1.x - 0.5f, dy = bb1.y - 0.5f;
            float dw = bb1.z - 1.0f, dh = bb1.w - 1.0f;
            acc += 1e-4f * (dx * dx + dy * dy + dw * dw + dh * dh);
            if (any1 <= 0.0f) { float q = ip1 * ip1; acc += q * q; }
        }
    }

    // Phase D: block reduction (wave64 shuffle, then LDS across 4 waves)
    #pragma unroll
    for (int off = 32; off > 0; off >>= 1)
        acc += __shfl_down(acc, off, 64);
    if ((tid & 63) == 0) wsum[tid >> 6] = acc;
    __syncthreads();
    if (tid == 0)
        part[b * SPLIT + spl] = wsum[0] + wsum[1] + wsum[2] + wsum[3];
}

__global__ __launch_bounds__(NTHREADS) void yolo_reduce_kernel(
    const float* __restrict__ part, float* __restrict__ out)
{
    const int tid = threadIdx.x;
    __shared__ float wsum[NTHREADS / 64];
    float s = 0.0f;
    #pragma unroll
    for (int k = 0; k < NPART / NTHREADS; k++)
        s += part[k * NTHREADS + tid];
    #pragma unroll
    for (int off = 32; off > 0; off >>= 1)
        s += __shfl_down(s, off, 64);
    if ((tid & 63) == 0) wsum[tid >> 6] = s;
    __syncthreads();
    if (tid == 0)
        out[0] = (wsum[0] + wsum[1] + wsum[2] + wsum[3]) * (1.0f / (float)GG);
}

extern "C" void kernel_launch(void* const* d_in, const int* in_sizes, int n_in,
                              void* d_out, int out_size, void* d_ws, size_t ws_size,
                              hipStream_t stream) {
    const float* bbox    = (const float*)d_in[0];
    const float* ioup    = (const float*)d_in[1];
    const float* score   = (const float*)d_in[2];
    const float* tgt     = (const float*)d_in[3];
    const float* anchors = (const float*)d_in[4];
    float* out  = (float*)d_out;
    float* part = (float*)d_ws;   // NPART floats; fully overwritten

    dim3 grid(BATCH, SPLIT);
    yolo_loss_kernel<<<grid, NTHREADS, 0, stream>>>(bbox, ioup, score, tgt,
                                                    anchors, part);
    yolo_reduce_kernel<<<1, NTHREADS, 0, stream>>>(part, out);
}